// Round 7
// baseline (343.715 us; speedup 1.0000x reference)
//
#include <hip/hip_runtime.h>

#define B_ 8
#define N_ 2048
#define FIN_ 512
#define FOUT_ 512

typedef __attribute__((ext_vector_type(8))) short short8;
typedef __attribute__((ext_vector_type(4))) float floatx4;
typedef __attribute__((ext_vector_type(4))) unsigned short ushortx4;
typedef __attribute__((ext_vector_type(8))) unsigned short ushortx8;

__device__ inline unsigned short f2bf(float f) {
    union { float f; unsigned int u; } x; x.f = f;
    unsigned int r = x.u + 0x7FFFu + ((x.u >> 16) & 1u);  // RNE
    return (unsigned short)(r >> 16);
}

__device__ inline void glds16(const void* g, void* l) {
    __builtin_amdgcn_global_load_lds(
        (const __attribute__((address_space(1))) void*)g,
        (__attribute__((address_space(3))) void*)l, 16, 0, 0);
}

// --- 1) Fused: dinv[b*N+i] = rsqrt(1 + sum_j A[b,i,j]);  Abf = bf16(A) ------
__global__ __launch_bounds__(256) void degree_cast_kernel(
    const float* __restrict__ A, float* __restrict__ dinv,
    unsigned short* __restrict__ Abf) {
    int row = blockIdx.x;                 // b*N + i
    size_t base = (size_t)row * N_;
    const float4* A4 = (const float4*)(A + base);
    int t = threadIdx.x;
    float4 v0 = A4[t];
    float4 v1 = A4[t + 256];
    ushortx4 p0, p1;
    p0[0] = f2bf(v0.x); p0[1] = f2bf(v0.y); p0[2] = f2bf(v0.z); p0[3] = f2bf(v0.w);
    p1[0] = f2bf(v1.x); p1[1] = f2bf(v1.y); p1[2] = f2bf(v1.z); p1[3] = f2bf(v1.w);
    *(ushortx4*)(Abf + base + t * 4) = p0;
    *(ushortx4*)(Abf + base + (t + 256) * 4) = p1;
    float s = v0.x + v0.y + v0.z + v0.w + v1.x + v1.y + v1.z + v1.w;
#pragma unroll
    for (int off = 32; off > 0; off >>= 1) s += __shfl_down(s, off, 64);
    __shared__ float red[4];
    if ((t & 63) == 0) red[t >> 6] = s;
    __syncthreads();
    if (t == 0) dinv[row] = rsqrtf(red[0] + red[1] + red[2] + red[3] + 1.0f);
}

// --- 2a) X -> bf16 -----------------------------------------------------------
__global__ __launch_bounds__(256) void castX_kernel(const float* __restrict__ X,
                                                    unsigned short* __restrict__ Xbf) {
    size_t e0 = ((size_t)blockIdx.x * 256 + threadIdx.x) * 8;
    float4 a0 = *(const float4*)(X + e0);
    float4 a1 = *(const float4*)(X + e0 + 4);
    float av[8] = {a0.x, a0.y, a0.z, a0.w, a1.x, a1.y, a1.z, a1.w};
    ushortx8 p;
#pragma unroll
    for (int r = 0; r < 8; ++r) p[r] = f2bf(av[r]);
    *(ushortx8*)(Xbf + e0) = p;
}

// --- 2b) Wt[n][k] = bf16(W[k][n]) -------------------------------------------
__global__ __launch_bounds__(256) void transposeW_kernel(const float* __restrict__ W,
                                                         unsigned short* __restrict__ Wt) {
    __shared__ float tile[32][33];
    int bx = blockIdx.x * 32;   // F_OUT block
    int by = blockIdx.y * 32;   // F_IN block
    int tx = threadIdx.x, ty = threadIdx.y;   // 32 x 8
#pragma unroll
    for (int r = 0; r < 32; r += 8)
        tile[ty + r][tx] = W[(size_t)(by + ty + r) * FOUT_ + bx + tx];
    __syncthreads();
#pragma unroll
    for (int r = 0; r < 32; r += 8)
        Wt[(size_t)(bx + ty + r) * FIN_ + by + tx] = f2bf(tile[tx][ty + r]);
}

// ============================================================================
// Swizzled LDS tile: rows of BK=64 bf16 (128 B = 8 chunks of 16 B).
// chunk' = chunk ^ (row & 7).  Staging thread t of issue u lands at flat byte
// u*4096 + t*16 -> row = u*32 + (t>>3), chunk' = t&7, so it fetches global
// chunk c = (t&7) ^ ((t>>3)&7).  SQ_LDS_BANK_CONFLICT = 0 (verified).
// ============================================================================

// --- 3) GEMM1: y^T = ((Xbf @ Wt^T + b) * d_node)^T  -> XwT (bf16)
//               AND  out_init[i,f] = d_i * y[i,f]    -> out (fp32)
// 128x128 tile, BK=64, phased 2-deep counted-vmcnt pipeline (best, round 3).
__global__ __launch_bounds__(256) void gemm1_kernel(
    const unsigned short* __restrict__ Abase,   // Xbf [16384][512]
    const unsigned short* __restrict__ Btbase,  // Wt  [512][512]
    unsigned short* __restrict__ XwT,           // [8][512][2048]  (= y^T)
    const float* __restrict__ bias,
    const float* __restrict__ dinv,             // [16384]
    float* __restrict__ out) {                  // [16384][512] fp32 (init term)
    __shared__ __align__(16) char smem[65536];  // 2 x (As 16KB + Bs 16KB); epi reuses

    int t = threadIdx.x;
    int lane = t & 63;
    int wave = t >> 6;
    int wr = wave >> 1, wc = wave & 1;
    int q = lane >> 4, m = lane & 15;
    int n0 = blockIdx.x * 128;   // FOUT block
    int m0 = blockIdx.y * 128;   // node block (flat b*N+node)

    int srow = t >> 3;                       // 0..31 per issue
    int scol = (((t & 7) ^ (srow & 7)) * 8); // global elem chunk start
    int x0 = ((q ^ (m & 7)) * 16);           // sub-slab 0 chunk byte
    int x1 = x0 ^ 64;                        // sub-slab 1

    floatx4 acc[4][4];
#pragma unroll
    for (int mi = 0; mi < 4; ++mi)
#pragma unroll
        for (int ni = 0; ni < 4; ++ni)
            acc[mi][ni] = (floatx4){0.f, 0.f, 0.f, 0.f};

    const unsigned short* gA = Abase + (size_t)(m0 + srow) * FIN_ + scol;
    const unsigned short* gB = Btbase + (size_t)(n0 + srow) * FIN_ + scol;

#define STAGE1(bufi) do {                                              \
        char* lA = smem + (bufi) * 32768 + wave * 1024;                \
        char* lB = smem + (bufi) * 32768 + 16384 + wave * 1024;        \
        _Pragma("unroll")                                              \
        for (int u = 0; u < 4; ++u) {                                  \
            glds16(gA + (size_t)(u * 32) * FIN_, lA + u * 4096);       \
            glds16(gB + (size_t)(u * 32) * FIN_, lB + u * 4096);       \
        }                                                              \
        gA += 64; gB += 64;                                            \
    } while (0)

    STAGE1(0);
    STAGE1(1);

    const int NT = FIN_ / 64;   // 8
    for (int kt = 0; kt < NT; ++kt) {
        if (kt < NT - 1) asm volatile("s_waitcnt vmcnt(8)" ::: "memory");
        else             asm volatile("s_waitcnt vmcnt(0)" ::: "memory");
        __builtin_amdgcn_sched_barrier(0);
        __builtin_amdgcn_s_barrier();                   // tile kt resident
        const char* As = smem + (kt & 1) * 32768;
        const char* Bs = As + 16384;
        short8 af0[4], bf0[4], af1[4], bf1[4];
#pragma unroll
        for (int mi = 0; mi < 4; ++mi)
            af0[mi] = *(const short8*)(As + (wr * 64 + mi * 16 + m) * 128 + x0);
#pragma unroll
        for (int ni = 0; ni < 4; ++ni)
            bf0[ni] = *(const short8*)(Bs + (wc * 64 + ni * 16 + m) * 128 + x0);
#pragma unroll
        for (int mi = 0; mi < 4; ++mi)
            af1[mi] = *(const short8*)(As + (wr * 64 + mi * 16 + m) * 128 + x1);
#pragma unroll
        for (int ni = 0; ni < 4; ++ni)
            bf1[ni] = *(const short8*)(Bs + (wc * 64 + ni * 16 + m) * 128 + x1);
        asm volatile("s_waitcnt lgkmcnt(8)" ::: "memory");  // sl0 frags landed
        __builtin_amdgcn_sched_barrier(0);
        __builtin_amdgcn_s_setprio(1);
#pragma unroll
        for (int mi = 0; mi < 4; ++mi)
#pragma unroll
            for (int ni = 0; ni < 4; ++ni)
                acc[mi][ni] = __builtin_amdgcn_mfma_f32_16x16x32_bf16(
                    af0[mi], bf0[ni], acc[mi][ni], 0, 0, 0);
        __builtin_amdgcn_s_setprio(0);
        asm volatile("s_waitcnt lgkmcnt(0)" ::: "memory");  // sl1 landed too
        __builtin_amdgcn_sched_barrier(0);
        __builtin_amdgcn_s_barrier();                   // all waves pulled kt
        if (kt + 2 < NT) STAGE1(kt & 1);                // overwrite consumed buf
        __builtin_amdgcn_sched_barrier(0);
        __builtin_amdgcn_s_setprio(1);
#pragma unroll
        for (int mi = 0; mi < 4; ++mi)
#pragma unroll
            for (int ni = 0; ni < 4; ++ni)
                acc[mi][ni] = __builtin_amdgcn_mfma_f32_16x16x32_bf16(
                    af1[mi], bf1[ni], acc[mi][ni], 0, 0, 0);
        __builtin_amdgcn_s_setprio(0);
    }
#undef STAGE1

    // ---- epilogue: y = (acc+bias)*d_node -> XwT(bf16) via LDS transpose;
    //                out_init = d_node * y  -> out (fp32, direct) ------------
    unsigned short* T = (unsigned short*)smem;  // [128][136]
#pragma unroll
    for (int mi = 0; mi < 4; ++mi) {
        int row = wr * 64 + mi * 16 + q * 4;       // node-local (4 consecutive)
        float4 dv = *(const float4*)(dinv + m0 + row);
        float dr[4] = {dv.x, dv.y, dv.z, dv.w};
#pragma unroll
        for (int ni = 0; ni < 4; ++ni) {
            int col = wc * 64 + ni * 16 + m;       // f-local
            float bv = bias[n0 + col];
            ushortx4 pk;
#pragma unroll
            for (int r = 0; r < 4; ++r) {
                float fv = (acc[mi][ni][r] + bv) * dr[r];   // y (fp32)
                pk[r] = f2bf(fv);
                out[(size_t)(m0 + row + r) * FOUT_ + (n0 + col)] = dr[r] * fv;
            }
            *(ushortx4*)(T + col * 136 + row) = pk;
        }
    }
    __syncthreads();
    int f  = t >> 1;             // 0..127
    int c0 = (t & 1) * 64;       // node half
    int bb = m0 >> 11;
    int node0 = (m0 & 2047) + c0;
    unsigned short* dst = XwT + ((size_t)bb * FOUT_ + n0 + f) * N_ + node0;
    const unsigned short* src = T + f * 136 + c0;
#pragma unroll
    for (int u = 0; u < 8; ++u)
        *(ushortx8*)(dst + u * 8) = *(const ushortx8*)(src + u * 8);
}

// --- 4) GEMM2: out[b,i,:] += d_i * (Abf[b,i,kh-half] @ y[b,kh-half])  -------
// SPLIT-K=2 at constant 128x128 tile, BK=64: 1024 blocks -> ~3 co-resident
// blocks/CU (m97 regime; VGPR capped via __launch_bounds__(256,3), LDS 32KB).
// out pre-initialized by gemm1 with d_i*y_i; halves accumulate via HW
// global_atomic_add_f32 (unsafeAtomicAdd; out slab is XCD-local, b = id&7).
__global__ __launch_bounds__(256, 3) void gemm2_kernel(
    const unsigned short* __restrict__ Abf,   // [8][2048][2048] raw bf16(A)
    const unsigned short* __restrict__ XwT,   // [8][512][2048]  (= y^T = B^T)
    const float* __restrict__ dinv,           // [16384]
    float* __restrict__ out) {                // [8][2048][512] fp32 (pre-init)
    __shared__ __align__(16) char smem[32768];
    char* As = smem;            // 128 x 128 B (swizzled) = 16 KB
    char* Bs = smem + 16384;    // 128 x 128 B (swizzled) = 16 KB

    int t = threadIdx.x;
    int lane = t & 63;
    int wave = t >> 6;
    int wr = wave >> 1, wc = wave & 1;
    int q = lane >> 4, m = lane & 15;

    int id = blockIdx.x;         // 1024 blocks
    int b  = id & 7;             // XCD pin
    int s  = (id >> 3) & 63;     // 0..63 within (batch, khalf)
    int kh = id >> 9;            // 0..1  K-half
    int n0 = (s & 3) * 128;      // n-siblings adjacent in time
    int m0 = (s >> 2) * 128;

    const unsigned short* Ab = Abf + (size_t)b * N_ * N_;
    const unsigned short* Bb = XwT + (size_t)b * FOUT_ * N_;

    int srow = t >> 3;
    int scol = (((t & 7) ^ (srow & 7)) * 8);
    int x0 = ((q ^ (m & 7)) * 16);
    int x1 = x0 ^ 64;

    floatx4 acc[4][4];
#pragma unroll
    for (int mi = 0; mi < 4; ++mi)
#pragma unroll
        for (int ni = 0; ni < 4; ++ni)
            acc[mi][ni] = (floatx4){0.f, 0.f, 0.f, 0.f};

    const unsigned short* gA = Ab + (size_t)(m0 + srow) * N_ + kh * 1024 + scol;
    const unsigned short* gB = Bb + (size_t)(n0 + srow) * N_ + kh * 1024 + scol;
    char* lA = As + wave * 1024;
    char* lB = Bs + wave * 1024;

    for (int kt = 0; kt < 16; ++kt) {         // K-half = 1024 = 16 x 64
#pragma unroll
        for (int u = 0; u < 4; ++u) {
            glds16(gA + (size_t)(u * 32) * N_, lA + u * 4096);
            glds16(gB + (size_t)(u * 32) * N_, lB + u * 4096);
        }
        gA += 64; gB += 64;
        __syncthreads();

#pragma unroll
        for (int sl = 0; sl < 2; ++sl) {
            int xs = sl ? x1 : x0;
            short8 af[4], bfr[4];
#pragma unroll
            for (int mi = 0; mi < 4; ++mi)
                af[mi] = *(const short8*)(As + (wr * 64 + mi * 16 + m) * 128 + xs);
#pragma unroll
            for (int ni = 0; ni < 4; ++ni)
                bfr[ni] = *(const short8*)(Bs + (wc * 64 + ni * 16 + m) * 128 + xs);
#pragma unroll
            for (int mi = 0; mi < 4; ++mi)
#pragma unroll
                for (int ni = 0; ni < 4; ++ni)
                    acc[mi][ni] = __builtin_amdgcn_mfma_f32_16x16x32_bf16(
                        af[mi], bfr[ni], acc[mi][ni], 0, 0, 0);
        }
        __syncthreads();
    }

    // C/D layout: col = lane&15, row = (lane>>4)*4 + reg
    // out[row,col] += d_row * acc   (y-term already in out via gemm1)
    float* C = out + (size_t)b * N_ * FOUT_;
#pragma unroll
    for (int mi = 0; mi < 4; ++mi) {
        int rowb = m0 + wr * 64 + mi * 16 + q * 4;
        float4 dv = *(const float4*)(dinv + b * N_ + rowb);
        float dr[4] = {dv.x, dv.y, dv.z, dv.w};
#pragma unroll
        for (int ni = 0; ni < 4; ++ni) {
            int col = n0 + wc * 64 + ni * 16 + m;
#pragma unroll
            for (int r = 0; r < 4; ++r)
                unsafeAtomicAdd(&C[(size_t)(rowb + r) * FOUT_ + col],
                                dr[r] * acc[mi][ni][r]);
        }
    }
}

extern "C" void kernel_launch(void* const* d_in, const int* in_sizes, int n_in,
                              void* d_out, int out_size, void* d_ws, size_t ws_size,
                              hipStream_t stream) {
    const float* X    = (const float*)d_in[0];   // [8,2048,512]
    const float* A    = (const float*)d_in[1];   // [8,2048,2048]
    const float* W    = (const float*)d_in[2];   // [512,512]
    const float* bias = (const float*)d_in[3];   // [512]
    float* out = (float*)d_out;                  // [8,2048,512] fp32
    char* ws = (char*)d_ws;

    float* dinv          = (float*)(ws);                              // 64 KB
    unsigned short* Xbf  = (unsigned short*)(ws + (1u << 16));        // 16 MB
    unsigned short* Wt   = (unsigned short*)(ws + (1u << 16) + 16777216u);           // 512 KB
    unsigned short* XwT  = (unsigned short*)(ws + (1u << 16) + 16777216u + 524288u); // 16 MB
    unsigned short* Abf  = (unsigned short*)(ws + (1u << 16) + 16777216u + 524288u + 16777216u); // 64 MB

    degree_cast_kernel<<<B_ * N_, 256, 0, stream>>>(A, dinv, Abf);
    castX_kernel<<<((size_t)B_ * N_ * FIN_) / 2048, 256, 0, stream>>>(X, Xbf);
    transposeW_kernel<<<dim3(FOUT_ / 32, FIN_ / 32), dim3(32, 8), 0, stream>>>(W, Wt);

    gemm1_kernel<<<dim3(FOUT_ / 128, (B_ * N_) / 128), 256, 0, stream>>>(
        Xbf, Wt, XwT, bias, dinv, out);

    gemm2_kernel<<<1024, 256, 0, stream>>>(Abf, XwT, dinv, out);
}

// Round 8
// 281.979 us; speedup vs baseline: 1.2189x; 1.2189x over previous
//
#include <hip/hip_runtime.h>

#define B_ 8
#define N_ 2048
#define FIN_ 512
#define FOUT_ 512

typedef __attribute__((ext_vector_type(8))) short short8;
typedef __attribute__((ext_vector_type(4))) float floatx4;
typedef __attribute__((ext_vector_type(4))) unsigned short ushortx4;
typedef __attribute__((ext_vector_type(8))) unsigned short ushortx8;

__device__ inline unsigned short f2bf(float f) {
    union { float f; unsigned int u; } x; x.f = f;
    unsigned int r = x.u + 0x7FFFu + ((x.u >> 16) & 1u);  // RNE
    return (unsigned short)(r >> 16);
}

__device__ inline void glds16(const void* g, void* l) {
    __builtin_amdgcn_global_load_lds(
        (const __attribute__((address_space(1))) void*)g,
        (__attribute__((address_space(3))) void*)l, 16, 0, 0);
}

// --- 1) FUSED PREP (one launch replaces degree_cast + castX + transposeW) ---
// Grid 16384 x 256.  Every block: dinv/Abf for A-row blockIdx.x.
// Blocks [0,4096):  additionally cast one 2048-elem X chunk to bf16.
// Blocks [0,256):   additionally transpose one 32x32 W tile to Wt (bf16).
// All three are streaming/BW work; fusing removes 2 serialized dispatches.
__global__ __launch_bounds__(256) void prep_kernel(
    const float* __restrict__ A, float* __restrict__ dinv,
    unsigned short* __restrict__ Abf,
    const float* __restrict__ X, unsigned short* __restrict__ Xbf,
    const float* __restrict__ W, unsigned short* __restrict__ Wt) {
    int row = blockIdx.x;                 // b*N + i
    int t = threadIdx.x;

    // ---- X cast (blocks 0..4095) ----
    if (row < 4096) {
        size_t e0 = ((size_t)row * 256 + t) * 8;
        float4 a0 = *(const float4*)(X + e0);
        float4 a1 = *(const float4*)(X + e0 + 4);
        float av[8] = {a0.x, a0.y, a0.z, a0.w, a1.x, a1.y, a1.z, a1.w};
        ushortx8 p;
#pragma unroll
        for (int r = 0; r < 8; ++r) p[r] = f2bf(av[r]);
        *(ushortx8*)(Xbf + e0) = p;
    }

    // ---- W transpose (blocks 0..255) ----
    __shared__ float tile[32][33];
    if (row < 256) {
        int bx = (row & 15) * 32;   // F_OUT block
        int by = (row >> 4) * 32;   // F_IN block
        int tx = t & 31, ty = t >> 5;   // 32 x 8
#pragma unroll
        for (int r = 0; r < 32; r += 8)
            tile[ty + r][tx] = W[(size_t)(by + ty + r) * FOUT_ + bx + tx];
        __syncthreads();
#pragma unroll
        for (int r = 0; r < 32; r += 8)
            Wt[(size_t)(bx + ty + r) * FIN_ + by + tx] = f2bf(tile[tx][ty + r]);
    }

    // ---- degree + A cast (all blocks) ----
    size_t base = (size_t)row * N_;
    const float4* A4 = (const float4*)(A + base);
    float4 v0 = A4[t];
    float4 v1 = A4[t + 256];
    ushortx4 p0, p1;
    p0[0] = f2bf(v0.x); p0[1] = f2bf(v0.y); p0[2] = f2bf(v0.z); p0[3] = f2bf(v0.w);
    p1[0] = f2bf(v1.x); p1[1] = f2bf(v1.y); p1[2] = f2bf(v1.z); p1[3] = f2bf(v1.w);
    *(ushortx4*)(Abf + base + t * 4) = p0;
    *(ushortx4*)(Abf + base + (t + 256) * 4) = p1;
    float s = v0.x + v0.y + v0.z + v0.w + v1.x + v1.y + v1.z + v1.w;
#pragma unroll
    for (int off = 32; off > 0; off >>= 1) s += __shfl_down(s, off, 64);
    __shared__ float red[4];
    if ((t & 63) == 0) red[t >> 6] = s;
    __syncthreads();
    if (t == 0) dinv[row] = rsqrtf(red[0] + red[1] + red[2] + red[3] + 1.0f);
}

// ============================================================================
// Swizzled LDS tile: rows of BK=64 bf16 (128 B = 8 chunks of 16 B).
// chunk' = chunk ^ (row & 7).  Staging thread t of issue u lands at flat byte
// u*4096 + t*16 -> row = u*32 + (t>>3), chunk' = t&7, so it fetches global
// chunk c = (t&7) ^ ((t>>3)&7).  SQ_LDS_BANK_CONFLICT = 0 (verified).
//
// Phased 2-deep pipeline (T3+T4+T5) — best measured structure (round 3):
//   prologue: stage tiles 0,1 (16 glds/wave in flight)
//   iter kt:  vmcnt(8)  -> tile kt landed (kt+1 stays in flight)
//             s_barrier -> tile kt resident for all waves
//             ds_read sl0 frags (8), ds_read sl1 frags (8)
//             lgkmcnt(8) -> sl0 landed (DS in-order); setprio(1); 16 MFMA sl0
//             lgkmcnt(0); s_barrier -> every wave PULLED tile kt
//             stage kt+2 into buf[kt&1] (just-consumed buffer)
//             setprio(1); 16 MFMA sl1   (kt+1 / kt+2 loads fly underneath)
// ============================================================================

// --- 2) GEMM1: y^T = ((Xbf @ Wt^T + b) * d_node)^T, 128x128 tile, BK=64 -----
__global__ __launch_bounds__(256) void gemm1_kernel(
    const unsigned short* __restrict__ Abase,   // Xbf [16384][512]
    const unsigned short* __restrict__ Btbase,  // Wt  [512][512]
    unsigned short* __restrict__ XwT,           // [8][512][2048]  (= y^T)
    const float* __restrict__ bias,
    const float* __restrict__ dinv) {           // [16384]
    __shared__ __align__(16) char smem[65536];  // 2 x (As 16KB + Bs 16KB); epi reuses

    int t = threadIdx.x;
    int lane = t & 63;
    int wave = t >> 6;
    int wr = wave >> 1, wc = wave & 1;
    int q = lane >> 4, m = lane & 15;
    int n0 = blockIdx.x * 128;   // FOUT block
    int m0 = blockIdx.y * 128;   // node block (flat b*N+node)

    int srow = t >> 3;                       // 0..31 per issue
    int scol = (((t & 7) ^ (srow & 7)) * 8); // global elem chunk start
    int x0 = ((q ^ (m & 7)) * 16);           // sub-slab 0 chunk byte
    int x1 = x0 ^ 64;                        // sub-slab 1

    floatx4 acc[4][4];
#pragma unroll
    for (int mi = 0; mi < 4; ++mi)
#pragma unroll
        for (int ni = 0; ni < 4; ++ni)
            acc[mi][ni] = (floatx4){0.f, 0.f, 0.f, 0.f};

    const unsigned short* gA = Abase + (size_t)(m0 + srow) * FIN_ + scol;
    const unsigned short* gB = Btbase + (size_t)(n0 + srow) * FIN_ + scol;

#define STAGE1(bufi) do {                                              \
        char* lA = smem + (bufi) * 32768 + wave * 1024;                \
        char* lB = smem + (bufi) * 32768 + 16384 + wave * 1024;        \
        _Pragma("unroll")                                              \
        for (int u = 0; u < 4; ++u) {                                  \
            glds16(gA + (size_t)(u * 32) * FIN_, lA + u * 4096);       \
            glds16(gB + (size_t)(u * 32) * FIN_, lB + u * 4096);       \
        }                                                              \
        gA += 64; gB += 64;                                            \
    } while (0)

    STAGE1(0);
    STAGE1(1);

    const int NT = FIN_ / 64;   // 8
    for (int kt = 0; kt < NT; ++kt) {
        if (kt < NT - 1) asm volatile("s_waitcnt vmcnt(8)" ::: "memory");
        else             asm volatile("s_waitcnt vmcnt(0)" ::: "memory");
        __builtin_amdgcn_sched_barrier(0);
        __builtin_amdgcn_s_barrier();                   // tile kt resident
        const char* As = smem + (kt & 1) * 32768;
        const char* Bs = As + 16384;
        short8 af0[4], bf0[4], af1[4], bf1[4];
#pragma unroll
        for (int mi = 0; mi < 4; ++mi)
            af0[mi] = *(const short8*)(As + (wr * 64 + mi * 16 + m) * 128 + x0);
#pragma unroll
        for (int ni = 0; ni < 4; ++ni)
            bf0[ni] = *(const short8*)(Bs + (wc * 64 + ni * 16 + m) * 128 + x0);
#pragma unroll
        for (int mi = 0; mi < 4; ++mi)
            af1[mi] = *(const short8*)(As + (wr * 64 + mi * 16 + m) * 128 + x1);
#pragma unroll
        for (int ni = 0; ni < 4; ++ni)
            bf1[ni] = *(const short8*)(Bs + (wc * 64 + ni * 16 + m) * 128 + x1);
        asm volatile("s_waitcnt lgkmcnt(8)" ::: "memory");  // sl0 frags landed
        __builtin_amdgcn_sched_barrier(0);
        __builtin_amdgcn_s_setprio(1);
#pragma unroll
        for (int mi = 0; mi < 4; ++mi)
#pragma unroll
            for (int ni = 0; ni < 4; ++ni)
                acc[mi][ni] = __builtin_amdgcn_mfma_f32_16x16x32_bf16(
                    af0[mi], bf0[ni], acc[mi][ni], 0, 0, 0);
        __builtin_amdgcn_s_setprio(0);
        asm volatile("s_waitcnt lgkmcnt(0)" ::: "memory");  // sl1 landed too
        __builtin_amdgcn_sched_barrier(0);
        __builtin_amdgcn_s_barrier();                   // all waves pulled kt
        if (kt + 2 < NT) STAGE1(kt & 1);                // overwrite consumed buf
        __builtin_amdgcn_sched_barrier(0);
        __builtin_amdgcn_s_setprio(1);
#pragma unroll
        for (int mi = 0; mi < 4; ++mi)
#pragma unroll
            for (int ni = 0; ni < 4; ++ni)
                acc[mi][ni] = __builtin_amdgcn_mfma_f32_16x16x32_bf16(
                    af1[mi], bf1[ni], acc[mi][ni], 0, 0, 0);
        __builtin_amdgcn_s_setprio(0);
    }
#undef STAGE1

    // ---- epilogue: (acc + bias) * dinv_node, transpose via LDS, store ------
    unsigned short* T = (unsigned short*)smem;  // [128][136]
#pragma unroll
    for (int mi = 0; mi < 4; ++mi) {
        int row = wr * 64 + mi * 16 + q * 4;       // node-local (4 consecutive)
        float4 dv = *(const float4*)(dinv + m0 + row);
        float dr[4] = {dv.x, dv.y, dv.z, dv.w};
#pragma unroll
        for (int ni = 0; ni < 4; ++ni) {
            int col = wc * 64 + ni * 16 + m;       // f-local
            float bv = bias[n0 + col];
            ushortx4 pk;
#pragma unroll
            for (int r = 0; r < 4; ++r) pk[r] = f2bf((acc[mi][ni][r] + bv) * dr[r]);
            *(ushortx4*)(T + col * 136 + row) = pk;
        }
    }
    __syncthreads();
    int f  = t >> 1;             // 0..127
    int c0 = (t & 1) * 64;       // node half
    int bb = m0 >> 11;
    int node0 = (m0 & 2047) + c0;
    unsigned short* dst = XwT + ((size_t)bb * FOUT_ + n0 + f) * N_ + node0;
    const unsigned short* src = T + f * 136 + c0;
#pragma unroll
    for (int u = 0; u < 8; ++u)
        *(ushortx8*)(dst + u * 8) = *(const ushortx8*)(src + u * 8);
}

// --- 3) GEMM2: out[b,i,:] = d_i * (Abf[b,i,:] @ y[b] + y[b,i,:]) ------------
// 128x128 tile, BK=64, swizzled LDS, XCD-aware 1D grid (batch = id & 7),
// phased 2-deep counted-vmcnt pipeline (best measured, round 3).
__global__ __launch_bounds__(256) void gemm2_kernel(
    const unsigned short* __restrict__ Abf,   // [8][2048][2048] raw bf16(A)
    const unsigned short* __restrict__ XwT,   // [8][512][2048]  (= y^T = B^T)
    const float* __restrict__ dinv,           // [16384]
    float* __restrict__ out) {                // [8][2048][512]
    __shared__ __align__(16) char smem[65536];  // 2 x (As 16KB + Bs 16KB)

    int t = threadIdx.x;
    int lane = t & 63;
    int wave = t >> 6;
    int wr = wave >> 1, wc = wave & 1;
    int q = lane >> 4, m = lane & 15;

    int id = blockIdx.x;
    int b  = id & 7;             // XCD pin
    int s  = id >> 3;            // 0..63 within batch
    int n0 = (s & 3) * 128;      // n-siblings adjacent in time
    int m0 = (s >> 2) * 128;

    const unsigned short* Ab = Abf + (size_t)b * N_ * N_;
    const unsigned short* Bb = XwT + (size_t)b * FOUT_ * N_;

    int srow = t >> 3;
    int scol = (((t & 7) ^ (srow & 7)) * 8);
    int x0 = ((q ^ (m & 7)) * 16);
    int x1 = x0 ^ 64;

    floatx4 acc[4][4];
#pragma unroll
    for (int mi = 0; mi < 4; ++mi)
#pragma unroll
        for (int ni = 0; ni < 4; ++ni)
            acc[mi][ni] = (floatx4){0.f, 0.f, 0.f, 0.f};

    const unsigned short* gA = Ab + (size_t)(m0 + srow) * N_ + scol;
    const unsigned short* gB = Bb + (size_t)(n0 + srow) * N_ + scol;

#define STAGE2(bufi) do {                                              \
        char* lA = smem + (bufi) * 32768 + wave * 1024;                \
        char* lB = smem + (bufi) * 32768 + 16384 + wave * 1024;        \
        _Pragma("unroll")                                              \
        for (int u = 0; u < 4; ++u) {                                  \
            glds16(gA + (size_t)(u * 32) * N_, lA + u * 4096);         \
            glds16(gB + (size_t)(u * 32) * N_, lB + u * 4096);         \
        }                                                              \
        gA += 64; gB += 64;                                            \
    } while (0)

    STAGE2(0);
    STAGE2(1);

    const int NT = N_ / 64;   // 32
    for (int kt = 0; kt < NT; ++kt) {
        if (kt < NT - 1) asm volatile("s_waitcnt vmcnt(8)" ::: "memory");
        else             asm volatile("s_waitcnt vmcnt(0)" ::: "memory");
        __builtin_amdgcn_sched_barrier(0);
        __builtin_amdgcn_s_barrier();                   // tile kt resident
        const char* As = smem + (kt & 1) * 32768;
        const char* Bs = As + 16384;
        short8 af0[4], bf0[4], af1[4], bf1[4];
#pragma unroll
        for (int mi = 0; mi < 4; ++mi)
            af0[mi] = *(const short8*)(As + (wr * 64 + mi * 16 + m) * 128 + x0);
#pragma unroll
        for (int ni = 0; ni < 4; ++ni)
            bf0[ni] = *(const short8*)(Bs + (wc * 64 + ni * 16 + m) * 128 + x0);
#pragma unroll
        for (int mi = 0; mi < 4; ++mi)
            af1[mi] = *(const short8*)(As + (wr * 64 + mi * 16 + m) * 128 + x1);
#pragma unroll
        for (int ni = 0; ni < 4; ++ni)
            bf1[ni] = *(const short8*)(Bs + (wc * 64 + ni * 16 + m) * 128 + x1);
        asm volatile("s_waitcnt lgkmcnt(8)" ::: "memory");  // sl0 frags landed
        __builtin_amdgcn_sched_barrier(0);
        __builtin_amdgcn_s_setprio(1);
#pragma unroll
        for (int mi = 0; mi < 4; ++mi)
#pragma unroll
            for (int ni = 0; ni < 4; ++ni)
                acc[mi][ni] = __builtin_amdgcn_mfma_f32_16x16x32_bf16(
                    af0[mi], bf0[ni], acc[mi][ni], 0, 0, 0);
        __builtin_amdgcn_s_setprio(0);
        asm volatile("s_waitcnt lgkmcnt(0)" ::: "memory");  // sl1 landed too
        __builtin_amdgcn_sched_barrier(0);
        __builtin_amdgcn_s_barrier();                   // all waves pulled kt
        if (kt + 2 < NT) STAGE2(kt & 1);                // overwrite consumed buf
        __builtin_amdgcn_sched_barrier(0);
        __builtin_amdgcn_s_setprio(1);
#pragma unroll
        for (int mi = 0; mi < 4; ++mi)
#pragma unroll
            for (int ni = 0; ni < 4; ++ni)
                acc[mi][ni] = __builtin_amdgcn_mfma_f32_16x16x32_bf16(
                    af1[mi], bf1[ni], acc[mi][ni], 0, 0, 0);
        __builtin_amdgcn_s_setprio(0);
    }
#undef STAGE2

    // C/D layout: col = lane&15, row = (lane>>4)*4 + reg
    // out_row = d_row * (acc_row + y_row[col]),  y = XwT[b][col][row] (bf16)
    float* C = out + (size_t)b * N_ * FOUT_;
#pragma unroll
    for (int mi = 0; mi < 4; ++mi) {
        int rowb = m0 + wr * 64 + mi * 16 + q * 4;
        float4 dv = *(const float4*)(dinv + b * N_ + rowb);
        float dr[4] = {dv.x, dv.y, dv.z, dv.w};
#pragma unroll
        for (int ni = 0; ni < 4; ++ni) {
            int col = n0 + wc * 64 + ni * 16 + m;
            ushortx4 yv = *(const ushortx4*)(Bb + (size_t)col * N_ + rowb);
#pragma unroll
            for (int r = 0; r < 4; ++r) {
                union { unsigned int u; float f; } yc; yc.u = ((unsigned int)yv[r]) << 16;
                C[(size_t)(rowb + r) * FOUT_ + col] = dr[r] * (acc[mi][ni][r] + yc.f);
            }
        }
    }
}

extern "C" void kernel_launch(void* const* d_in, const int* in_sizes, int n_in,
                              void* d_out, int out_size, void* d_ws, size_t ws_size,
                              hipStream_t stream) {
    const float* X    = (const float*)d_in[0];   // [8,2048,512]
    const float* A    = (const float*)d_in[1];   // [8,2048,2048]
    const float* W    = (const float*)d_in[2];   // [512,512]
    const float* bias = (const float*)d_in[3];   // [512]
    float* out = (float*)d_out;                  // [8,2048,512] fp32
    char* ws = (char*)d_ws;

    float* dinv          = (float*)(ws);                              // 64 KB
    unsigned short* Xbf  = (unsigned short*)(ws + (1u << 16));        // 16 MB
    unsigned short* Wt   = (unsigned short*)(ws + (1u << 16) + 16777216u);           // 512 KB
    unsigned short* XwT  = (unsigned short*)(ws + (1u << 16) + 16777216u + 524288u); // 16 MB
    unsigned short* Abf  = (unsigned short*)(ws + (1u << 16) + 16777216u + 524288u + 16777216u); // 64 MB

    prep_kernel<<<B_ * N_, 256, 0, stream>>>(A, dinv, Abf, X, Xbf, W, Wt);

    gemm1_kernel<<<dim3(FOUT_ / 128, (B_ * N_) / 128), 256, 0, stream>>>(
        Xbf, Wt, XwT, bias, dinv);

    gemm2_kernel<<<512, 256, 0, stream>>>(Abf, XwT, dinv, out);
}